// Round 3
// baseline (16741.008 us; speedup 1.0000x reference)
//
#include <hip/hip_runtime.h>
#include <cfloat>
#include <cmath>

// ---- problem constants ----
constexpr int kV   = 50257;
constexpr int kVP  = 50432;   // padded vocab stride for embT
constexpr int BB   = 4;
constexpr int BEAM = 5;
constexpr int RR   = 20;
constexpr int BUFL = 17;
constexpr int TMAX = 16;
constexpr int SOS  = 1;
constexpr int EOSt = 2;
constexpr int LB   = (kV + 255) / 256;  // 197 logits chunks
constexpr int CSEG = RR * BUFL * 768;   // per (parity,layer) cache segment
#define NEGV (-1e20f)

// ---------------- wave helpers ----------------
__device__ __forceinline__ float wave_sum(float v) {
#pragma unroll
  for (int o = 32; o > 0; o >>= 1) v += __shfl_xor(v, o, 64);
  return v;
}
__device__ __forceinline__ float wave_max(float v) {
#pragma unroll
  for (int o = 32; o > 0; o >>= 1) v = fmaxf(v, __shfl_xor(v, o, 64));
  return v;
}
__device__ __forceinline__ bool better(float v1, int i1, float v2, int i2) {
  return v1 > v2 || (v1 == v2 && i1 < i2);
}
__device__ __forceinline__ void insert5(float* tv, int* ti, float v, int i) {
  if (better(v, i, tv[4], ti[4])) {
    tv[4] = v; ti[4] = i;
#pragma unroll
    for (int s = 4; s > 0; --s)
      if (better(tv[s], ti[s], tv[s - 1], ti[s - 1])) {
        float fv = tv[s]; tv[s] = tv[s - 1]; tv[s - 1] = fv;
        int iv = ti[s]; ti[s] = ti[s - 1]; ti[s - 1] = iv;
      }
  }
}
__device__ __forceinline__ float sel5f(const float* a, int i) {
  float r = a[0];
  r = (i == 1) ? a[1] : r; r = (i == 2) ? a[2] : r;
  r = (i == 3) ? a[3] : r; r = (i == 4) ? a[4] : r;
  return r;
}
__device__ __forceinline__ int sel5i(const int* a, int i) {
  int r = a[0];
  r = (i == 1) ? a[1] : r; r = (i == 2) ? a[2] : r;
  r = (i == 3) ? a[3] : r; r = (i == 4) ? a[4] : r;
  return r;
}
__device__ __forceinline__ void merge5(float* av, int* ai, const float* bv, const int* bi) {
  float cv[5]; int ci[5];
  int ia = 0, ib = 0;
#pragma unroll
  for (int s = 0; s < 5; ++s) {
    float va = sel5f(av, ia); int xa = sel5i(ai, ia);
    float vb = sel5f(bv, ib); int xb = sel5i(bi, ib);
    bool ta = better(va, xa, vb, xb);
    cv[s] = ta ? va : vb; ci[s] = ta ? xa : xb;
    ia += ta ? 1 : 0; ib += ta ? 0 : 1;
  }
#pragma unroll
  for (int s = 0; s < 5; ++s) { av[s] = cv[s]; ai[s] = ci[s]; }
}

// ---------------- params ----------------
struct KParams {
  const float *emb, *pos, *lneg, *lneb;
  const float *siW, *siB, *soW, *soB, *ciW, *ciB, *coW, *coB;
  const float *f1W, *f1B, *f2W, *f2B;
  const float *ln1g, *ln1b, *ln2g, *ln2b, *ln3g, *ln3b;
  const float *dW, *dB, *ctx;
  const int* smask;
  float *XA, *XB, *XC, *qb, *attnb, *tmp, *hbuf, *ffb;
  float *fp0, *fp1, *fp2, *fp3;
  float *candV, *mrow, *srow, *scores, *ck, *cv, *kcB, *vcB;
  int *candI, *bufs0, *bufs1, *prevK, *tokv;
  int *arrive, *release;
  float *out;
  float *siT, *soT, *ciT, *coT, *f1T, *f2T, *dT, *embT;
  int useWT, useET;
};

// ---------------- grid barrier ----------------
__device__ __forceinline__ void gbar(int* arr, int* rel, int& ph) {
  ++ph;
  __syncthreads();
  if (threadIdx.x == 0) {
    __threadfence();   // writeback this XCD's L2 (release)
    __hip_atomic_store(&arr[blockIdx.x], ph, __ATOMIC_RELAXED, __HIP_MEMORY_SCOPE_AGENT);
  }
  if (blockIdx.x == 0) {
    while (__hip_atomic_load(&arr[threadIdx.x], __ATOMIC_RELAXED, __HIP_MEMORY_SCOPE_AGENT) < ph)
      __builtin_amdgcn_s_sleep(2);
    __syncthreads();
    if (threadIdx.x == 0) {
      __threadfence();  // invalidate before rel store; also release for rel
      __hip_atomic_store(rel, ph, __ATOMIC_RELAXED, __HIP_MEMORY_SCOPE_AGENT);
    }
    __syncthreads();
  } else {
    if (threadIdx.x == 0) {
      while (__hip_atomic_load(rel, __ATOMIC_RELAXED, __HIP_MEMORY_SCOPE_AGENT) < ph)
        __builtin_amdgcn_s_sleep(2);
      __threadfence();  // invalidate L1/L2 (acquire)
    }
    __syncthreads();
  }
}

// ---------------- transposes (setup phase) ----------------
__device__ void do_transposes(const KParams& P, float* SM) {
  const float* srcs[14]; float* dsts[14]; int Rs[14], Cs[14], dss[14];
  int nj = 0;
  for (int l = 0; l < 2; ++l) { srcs[nj]=P.siW + (size_t)l*2304*768; dsts[nj]=P.siT + (size_t)l*768*2304; Rs[nj]=2304; Cs[nj]=768; dss[nj]=2304; ++nj; }
  for (int l = 0; l < 2; ++l) { srcs[nj]=P.soW + (size_t)l*768*768;  dsts[nj]=P.soT + (size_t)l*768*768;  Rs[nj]=768;  Cs[nj]=768; dss[nj]=768;  ++nj; }
  for (int l = 0; l < 2; ++l) { srcs[nj]=P.ciW + (size_t)l*2304*768; dsts[nj]=P.ciT + (size_t)l*768*2304; Rs[nj]=2304; Cs[nj]=768; dss[nj]=2304; ++nj; }
  for (int l = 0; l < 2; ++l) { srcs[nj]=P.coW + (size_t)l*768*768;  dsts[nj]=P.coT + (size_t)l*768*768;  Rs[nj]=768;  Cs[nj]=768; dss[nj]=768;  ++nj; }
  for (int l = 0; l < 2; ++l) { srcs[nj]=P.f1W + (size_t)l*3072*768; dsts[nj]=P.f1T + (size_t)l*768*3072; Rs[nj]=3072; Cs[nj]=768; dss[nj]=3072; ++nj; }
  for (int l = 0; l < 2; ++l) { srcs[nj]=P.f2W + (size_t)l*768*3072; dsts[nj]=P.f2T + (size_t)l*3072*768; Rs[nj]=768;  Cs[nj]=3072; dss[nj]=768; ++nj; }
  srcs[nj]=P.dW; dsts[nj]=P.dT; Rs[nj]=768; Cs[nj]=768; dss[nj]=768; ++nj;
  if (P.useET) { srcs[nj]=P.emb; dsts[nj]=P.embT; Rs[nj]=kV; Cs[nj]=768; dss[nj]=kVP; ++nj; }
  int tcnt[14], tot = 0;
  for (int j = 0; j < nj; ++j) { tcnt[j] = ((Rs[j]+31)/32) * ((Cs[j]+31)/32); tot += tcnt[j]; }
  const int tid = threadIdx.x;
  const int lx = tid & 31, ly = tid >> 5;
  for (int jt = blockIdx.x; jt < tot; jt += 256) {
    int j = 0, lt = jt;
    while (lt >= tcnt[j]) { lt -= tcnt[j]; ++j; }
    int ct = (Cs[j] + 31) / 32;
    int tr = lt / ct, tc = lt - tr * ct;
    const float* src = srcs[j]; float* dst = dsts[j];
    int R = Rs[j], C = Cs[j], ds = dss[j];
    int r0 = tr * 32, c0 = tc * 32;
    __syncthreads();
#pragma unroll
    for (int q = 0; q < 4; ++q) {
      int r = r0 + ly + q * 8;
      if (r < R && c0 + lx < C) SM[(ly + q * 8) * 33 + lx] = src[(size_t)r * C + c0 + lx];
    }
    __syncthreads();
#pragma unroll
    for (int q = 0; q < 4; ++q) {
      int c = c0 + ly + q * 8;
      if (c < C && r0 + lx < R) dst[(size_t)c * ds + r0 + lx] = SM[lx * 33 + ly + q * 8];
    }
  }
}

// ---------------- cross K/V (setup phase) ----------------
template<bool WT>
__device__ void do_crosskv(const KParams& P, float* SM) {
  float* a_s = SM;            // 12288
  float* ps  = SM + 12288;    // 4096
  const int tid = threadIdx.x;
  const int w = tid >> 6, lane = tid & 63;
  for (int i5 = 0; i5 < 6; ++i5) {
    int j = blockIdx.x + 256 * i5;     // 1536 jobs exactly
    int cx = j % 24, ry = (j / 24) % 32, l = j / 768;
    const float* Wt = P.ciT + (size_t)l * 768 * 2304;
    const float* Wg = P.ciW + (size_t)l * 2304 * 768;
    const float* bias = P.ciB + l * 2304;
    const int row0 = ry * 16;
    __syncthreads();
    for (int i = tid * 4; i < 16 * 768; i += 1024) {
      int rr = i / 768, k = i - rr * 768;
      *(float4*)&a_s[i] = *(const float4*)&P.ctx[(size_t)(row0 + rr) * 768 + k];
    }
    __syncthreads();
    const int colg = 768 + cx * 64 + lane;
    const int kb = w * 192;
    float acc[16];
#pragma unroll
    for (int r = 0; r < 16; ++r) acc[r] = 0.f;
    for (int k4 = 0; k4 < 48; ++k4) {
      const int k = kb + k4 * 4;
      float w0, w1, w2, w3;
      if (WT) {
        const float* wr = Wt + (size_t)k * 2304 + colg;
        w0 = wr[0]; w1 = wr[2304]; w2 = wr[2 * 2304]; w3 = wr[3 * 2304];
      } else {
        float4 wv = *(const float4*)&Wg[(size_t)colg * 768 + k];
        w0 = wv.x; w1 = wv.y; w2 = wv.z; w3 = wv.w;
      }
#pragma unroll
      for (int r = 0; r < 16; ++r) {
        float4 a = *(const float4*)&a_s[r * 768 + k];
        acc[r] = fmaf(a.x, w0, fmaf(a.y, w1, fmaf(a.z, w2, fmaf(a.w, w3, acc[r]))));
      }
    }
#pragma unroll
    for (int r = 0; r < 16; ++r) ps[(w * 64 + lane) * 16 + r] = acc[r];
    __syncthreads();
    for (int o = tid; o < 1024; o += 256) {
      int rr = o >> 6, cl = o & 63;
      int cg = 768 + cx * 64 + cl;
      float v = bias[cg];
#pragma unroll
      for (int ww = 0; ww < 4; ++ww) v += ps[(ww * 64 + cl) * 16 + rr];
      int gr = row0 + rr;
      int b = gr >> 7, s = gr & 127;
      int c = cg - 768, kv = c / 768, n = c - kv * 768;
      float* dst = kv ? P.cv : P.ck;
      dst[((size_t)(l * 4 + b) * 128 + s) * 768 + n] = v;
    }
  }
}

// ---------------- fused gemm tile (M=20, K=768 view, 128 cols, 2 row-passes) ----------------
template<bool WT>
__device__ void gemm_tile(
    float* SM, int tile,
    const float* Wt, int wstride, const float* Wg, int wgK, int wRowOff,
    const float* bias, bool addBias,
    int pre, const float* aBase, int aStride,
    const float* xsrc, const float* const* parts, int nparts,
    const float* lng, const float* lnb, float* xout,
    int outmode, float* out0, int Nout,
    float* kNew, float* vNew, int t, const int* bufc,
    const float* embw, const float* posw)
{
  float* a_s = SM;                  // 7680
  float* ps  = SM + 7680;           // 5120
  float* mS  = SM + 12800;          // 20
  float* rS  = SM + 12820;          // 20
  int* tokS  = (int*)(SM + 12840);  // 20
  const int tid = threadIdx.x;
  const int w = tid >> 6, lane = tid & 63;
  if (pre == 1 && tid < RR) tokS[tid] = bufc[tid * BUFL + t];
  __syncthreads();
  for (int rp = 0; rp < 2; ++rp) {
    const int r0 = rp * 10;
    for (int i = tid * 4; i < 7680; i += 1024) {
      int rl = i / 768, k = i - rl * 768, r = r0 + rl;
      float4 v;
      if (pre == 0) v = *(const float4*)&aBase[(size_t)r * aStride + k];
      else if (pre == 1) {
        float4 e = *(const float4*)&embw[(size_t)tokS[r] * 768 + k];
        float4 p = *(const float4*)&posw[(size_t)t * 768 + k];
        v = make_float4(e.x + p.x, e.y + p.y, e.z + p.z, e.w + p.w);
      } else {
        v = *(const float4*)&xsrc[r * 768 + k];
        for (int q = 0; q < nparts; ++q) {
          float4 u = *(const float4*)&parts[q][r * 768 + k];
          v.x += u.x; v.y += u.y; v.z += u.z; v.w += u.w;
        }
      }
      *(float4*)&a_s[i] = v;
    }
    __syncthreads();
    if (pre != 0) {
      for (int rl = w; rl < 10; rl += 4) {
        float s = 0.f, q = 0.f;
        for (int k = lane; k < 768; k += 64) { float v = a_s[rl * 768 + k]; s += v; q += v * v; }
        s = wave_sum(s); q = wave_sum(q);
        if (lane == 0) {
          float m = s / 768.f;
          mS[rl] = m; rS[rl] = 1.f / sqrtf(q / 768.f - m * m + 1e-5f);
        }
      }
      __syncthreads();
      for (int i = tid * 4; i < 7680; i += 1024) {
        int rl = i / 768, k = i - rl * 768;
        float4 v = *(const float4*)&a_s[i];
        float4 g = *(const float4*)&lng[k];
        float4 b = *(const float4*)&lnb[k];
        float m = mS[rl], rs = rS[rl];
        v = make_float4((v.x - m) * rs * g.x + b.x, (v.y - m) * rs * g.y + b.y,
                        (v.z - m) * rs * g.z + b.z, (v.w - m) * rs * g.w + b.w);
        *(float4*)&a_s[i] = v;
        if (xout != nullptr && tile == 0) *(float4*)&xout[(r0 + rl) * 768 + k] = v;
      }
      __syncthreads();
    }
    const int c0 = tile * 128 + lane;
    const int kb = w * 192;
    float acc0[10], acc1[10];
#pragma unroll
    for (int rl = 0; rl < 10; ++rl) { acc0[rl] = 0.f; acc1[rl] = 0.f; }
    for (int k4 = 0; k4 < 48; ++k4) {
      const int k = kb + k4 * 4, kg = wRowOff + k;
      float wa0, wa1, wa2, wa3, wb0, wb1, wb2, wb3;
      if (WT) {
        const float* wr = Wt + (size_t)kg * wstride;
        wa0 = wr[c0]; wb0 = wr[c0 + 64]; wr += wstride;
        wa1 = wr[c0]; wb1 = wr[c0 + 64]; wr += wstride;
        wa2 = wr[c0]; wb2 = wr[c0 + 64]; wr += wstride;
        wa3 = wr[c0]; wb3 = wr[c0 + 64];
      } else {
        float4 A4 = *(const float4*)&Wg[(size_t)c0 * wgK + kg];
        float4 B4 = *(const float4*)&Wg[(size_t)(c0 + 64) * wgK + kg];
        wa0 = A4.x; wa1 = A4.y; wa2 = A4.z; wa3 = A4.w;
        wb0 = B4.x; wb1 = B4.y; wb2 = B4.z; wb3 = B4.w;
      }
#pragma unroll
      for (int rl = 0; rl < 10; ++rl) {
        float4 a = *(const float4*)&a_s[rl * 768 + k];
        acc0[rl] = fmaf(a.x, wa0, fmaf(a.y, wa1, fmaf(a.z, wa2, fmaf(a.w, wa3, acc0[rl]))));
        acc1[rl] = fmaf(a.x, wb0, fmaf(a.y, wb1, fmaf(a.z, wb2, fmaf(a.w, wb3, acc1[rl]))));
      }
    }
#pragma unroll
    for (int rl = 0; rl < 10; ++rl) {
      ps[(w * 128 + lane) * 10 + rl] = acc0[rl];
      ps[(w * 128 + 64 + lane) * 10 + rl] = acc1[rl];
    }
    __syncthreads();
    for (int o = tid; o < 1280; o += 256) {
      int rl = o >> 7, cl = o & 127;
      int r = r0 + rl, cg = tile * 128 + cl;
      float v = addBias ? bias[cg] : 0.f;
#pragma unroll
      for (int ww = 0; ww < 4; ++ww) v += ps[(ww * 128 + cl) * 10 + rl];
      if (outmode == 1) v = fmaxf(v, 0.f);
      else if (outmode == 2) v = tanhf(v);
      if (outmode == 3) {
        if (cg < 768) out0[r * 768 + cg] = v;
        else if (cg < 1536) kNew[(r * BUFL + t) * 768 + (cg - 768)] = v;
        else vNew[(r * BUFL + t) * 768 + (cg - 1536)] = v;
      } else {
        out0[(size_t)r * Nout + cg] = v;
      }
    }
    __syncthreads();
  }
}

// ---------------- self-attention phase (bid<60; wave = (r,h) job) ----------------
__device__ void self_attn_phase(const KParams& P, float* SM, const float* kc, const float* vc, int t) {
  const int tid = threadIdx.x;
  const int w = tid >> 6, lane = tid & 63;
  const int idx = blockIdx.x * 4 + w;
  const int r = idx / 12, hh = idx - (idx / 12) * 12;
  float* qsw = SM + w * 64;
  float* ppw = SM + 256 + w * 128;
  qsw[lane] = P.qb[r * 768 + hh * 64 + lane];
  __syncthreads();
  float s = -1e30f;
  if (lane <= t) {
    const float* kr = kc + (size_t)(r * BUFL + lane) * 768 + hh * 64;
    float a = 0.f;
#pragma unroll
    for (int d4 = 0; d4 < 16; ++d4) {
      float4 kk = *(const float4*)&kr[d4 * 4];
      float4 qq = *(const float4*)&qsw[d4 * 4];
      a = fmaf(qq.x, kk.x, fmaf(qq.y, kk.y, fmaf(qq.z, kk.z, fmaf(qq.w, kk.w, a))));
    }
    s = a * 0.125f;
  }
  float m = wave_max(s);
  float p = expf(s - m);
  float sum = wave_sum(p);
  ppw[lane] = p / sum;
  __syncthreads();
  const float* vb = vc + (size_t)r * BUFL * 768 + hh * 64 + lane;
  float o = 0.f;
  for (int k = 0; k <= t; ++k) o = fmaf(ppw[k], vb[k * 768], o);
  P.attnb[r * 768 + hh * 64 + lane] = o;
}

// ---------------- cross-attention phase (bid<60) ----------------
__device__ void cross_attn_phase(const KParams& P, float* SM, const float* ck, const float* cv) {
  const int tid = threadIdx.x;
  const int w = tid >> 6, lane = tid & 63;
  const int idx = blockIdx.x * 4 + w;
  const int r = idx / 12, hh = idx - (idx / 12) * 12;
  const int b = r / BEAM;
  float* qsw = SM + w * 64;
  float* ppw = SM + 256 + w * 128;
  qsw[lane] = P.qb[r * 768 + hh * 64 + lane];
  __syncthreads();
  float a0 = 0.f, a1 = 0.f;
  const float* k0 = ck + (size_t)(b * 128 + lane) * 768 + hh * 64;
  const float* k1 = k0 + (size_t)64 * 768;
#pragma unroll
  for (int d4 = 0; d4 < 16; ++d4) {
    float4 qq = *(const float4*)&qsw[d4 * 4];
    float4 kk = *(const float4*)&k0[d4 * 4];
    float4 k2 = *(const float4*)&k1[d4 * 4];
    a0 = fmaf(qq.x, kk.x, fmaf(qq.y, kk.y, fmaf(qq.z, kk.z, fmaf(qq.w, kk.w, a0))));
    a1 = fmaf(qq.x, k2.x, fmaf(qq.y, k2.y, fmaf(qq.z, k2.z, fmaf(qq.w, k2.w, a1))));
  }
  float s0 = a0 * 0.125f, s1 = a1 * 0.125f;
  if (P.smask[b * 128 + lane] == 0)      s0 = -1e9f;
  if (P.smask[b * 128 + lane + 64] == 0) s1 = -1e9f;
  float m = wave_max(fmaxf(s0, s1));
  float p0 = expf(s0 - m), p1 = expf(s1 - m);
  float sum = wave_sum(p0 + p1);
  ppw[lane] = p0 / sum; ppw[lane + 64] = p1 / sum;
  __syncthreads();
  const float* vb = cv + (size_t)b * 128 * 768 + hh * 64 + lane;
  float o0 = 0.f, o1 = 0.f;
  for (int k = 0; k < 128; k += 2) {
    o0 = fmaf(ppw[k], vb[k * 768], o0);
    o1 = fmaf(ppw[k + 1], vb[(k + 1) * 768], o1);
  }
  P.attnb[r * 768 + hh * 64 + lane] = o0 + o1;
}

// ---------------- logits phase (bid<197) ----------------
template<bool ET>
__device__ void logits_phase(const KParams& P, float* SM) {
  float* hs = SM;           // 15360
  float* vv = SM + 15360;   // 1024
  const int tid = threadIdx.x, blk = blockIdx.x;
  for (int i = tid * 4; i < RR * 768; i += 1024)
    *(float4*)&hs[i] = *(const float4*)&P.hbuf[i];
  __syncthreads();
  const int col = blk * 256 + tid;
  const bool valid = col < kV;
  const int colc = valid ? col : (kV - 1);
  float acc[RR];
#pragma unroll
  for (int r = 0; r < RR; ++r) acc[r] = 0.f;
  for (int k = 0; k < 768; k += 4) {
    float w0, w1, w2, w3;
    if (ET) {
      w0 = P.embT[(size_t)(k + 0) * kVP + col]; w1 = P.embT[(size_t)(k + 1) * kVP + col];
      w2 = P.embT[(size_t)(k + 2) * kVP + col]; w3 = P.embT[(size_t)(k + 3) * kVP + col];
    } else {
      float4 wv = *(const float4*)&P.emb[(size_t)colc * 768 + k];
      w0 = wv.x; w1 = wv.y; w2 = wv.z; w3 = wv.w;
    }
#pragma unroll
    for (int r = 0; r < RR; ++r) {
      float4 a = *(const float4*)&hs[r * 768 + k];
      acc[r] = fmaf(a.x, w0, fmaf(a.y, w1, fmaf(a.z, w2, fmaf(a.w, w3, acc[r]))));
    }
  }
  const int w = tid >> 6, lane = tid & 63;
  for (int g = 0; g < 5; ++g) {
#pragma unroll
    for (int j = 0; j < 4; ++j) vv[j * 256 + tid] = valid ? acc[g * 4 + j] : -FLT_MAX;
    __syncthreads();
    const int r = g * 4 + w;
    float v[4]; int gc[4]; bool used[4];
#pragma unroll
    for (int j = 0; j < 4; ++j) {
      v[j] = vv[w * 256 + lane * 4 + j];
      gc[j] = blk * 256 + lane * 4 + j;
      used[j] = false;
    }
    float tv[5]; int tg[5];
#pragma unroll
    for (int round = 0; round < 5; ++round) {
      float bv = -FLT_MAX; int bidx = 0x7fffffff; int bj = -1;
#pragma unroll
      for (int j = 0; j < 4; ++j) {
        bool c = (!used[j]) && better(v[j], gc[j], bv, bidx);
        bv = c ? v[j] : bv; bidx = c ? gc[j] : bidx; bj = c ? j : bj;
      }
      float wv2 = bv; int wi = bidx;
      for (int d = 1; d < 64; d <<= 1) {
        float ov = __shfl_xor(wv2, d, 64); int oi = __shfl_xor(wi, d, 64);
        if (better(ov, oi, wv2, wi)) { wv2 = ov; wi = oi; }
      }
      tv[round] = wv2; tg[round] = wi;
      if (bj >= 0 && bidx == wi) used[bj] = true;
    }
    float m = tv[0];
    float s = 0.f;
#pragma unroll
    for (int j = 0; j < 4; ++j) s += expf(v[j] - m);
    s = wave_sum(s);
    if (lane == 0) {
      P.mrow[r * LB + blk] = m;
      P.srow[r * LB + blk] = s;
#pragma unroll
      for (int q = 0; q < 5; ++q) {
        P.candV[(r * LB + blk) * 5 + q] = tv[q];
        P.candI[(r * LB + blk) * 5 + q] = tg[q];
      }
    }
    __syncthreads();
  }
}

// ---------------- topk phase (bid<4) ----------------
__device__ void topk_phase(const KParams& P, float* SM, const int* bufc, int* bufn, int t) {
  const int b = blockIdx.x, tid = threadIdx.x;
  const int w = tid >> 6, lane = tid & 63;
  float* lseS = SM;               // 5
  float* scS  = SM + 8;           // 5
  int*   emS  = (int*)(SM + 16);  // 5
  float* wv5  = SM + 24;          // 20
  int*   wi5  = (int*)(SM + 44);  // 20
  int*   fpk  = (int*)(SM + 64);  // 5
  int*   ftok = (int*)(SM + 72);  // 5
  for (int j = w; j < 5; j += 4) {
    const int gr = b * 5 + j;
    float M = -FLT_MAX, S = 0.f;
    for (int e = lane; e < LB; e += 64) {
      float m2 = P.mrow[gr * LB + e], s2 = P.srow[gr * LB + e];
      if (m2 > M) { S = S * expf(M - m2) + s2; M = m2; }
      else        { S += s2 * expf(m2 - M); }
    }
    for (int d = 1; d < 64; d <<= 1) {
      float Mo = __shfl_xor(M, d, 64), So = __shfl_xor(S, d, 64);
      float Mn = fmaxf(M, Mo);
      S = S * expf(M - Mn) + So * expf(Mo - Mn);
      M = Mn;
    }
    if (lane == 0) {
      lseS[j] = M + logf(S);
      scS[j] = P.scores[gr];
      emS[j] = (bufc[gr * BUFL + t] == EOSt);
    }
  }
  __syncthreads();
  float tv[5]; int ti[5];
#pragma unroll
  for (int s = 0; s < 5; ++s) { tv[s] = -FLT_MAX; ti[s] = 0x7fffffff; }
  for (int i = tid; i < 5 * LB * 5; i += 256) {
    int j = i / (LB * 5);
    int e = i - j * (LB * 5);
    int blk = e / 5, rk = e - blk * 5;
    int gr = b * 5 + j;
    float cvv = P.candV[(gr * LB + blk) * 5 + rk];
    int col = P.candI[(gr * LB + blk) * 5 + rk];
    float val = emS[j] ? NEGV : (cvv - lseS[j] + scS[j]);
    insert5(tv, ti, val, j * kV + col);
  }
  for (int d = 1; d < 64; d <<= 1) {
    float ov[5]; int oi[5];
#pragma unroll
    for (int s = 0; s < 5; ++s) { ov[s] = __shfl_xor(tv[s], d, 64); oi[s] = __shfl_xor(ti[s], d, 64); }
    merge5(tv, ti, ov, oi);
  }
  if (lane == 0) {
#pragma unroll
    for (int s = 0; s < 5; ++s) { wv5[w * 5 + s] = tv[s]; wi5[w * 5 + s] = ti[s]; }
  }
  __syncthreads();
  if (tid == 0) {
    float av[5]; int ai[5];
#pragma unroll
    for (int s = 0; s < 5; ++s) { av[s] = wv5[s]; ai[s] = wi5[s]; }
    for (int ww = 1; ww < 4; ++ww) {
      float bv[5]; int bi[5];
#pragma unroll
      for (int s = 0; s < 5; ++s) { bv[s] = wv5[ww * 5 + s]; bi[s] = wi5[ww * 5 + s]; }
      merge5(av, ai, bv, bi);
    }
#pragma unroll
    for (int s = 0; s < 5; ++s) {
      int pk = ai[s] / kV;
      int tk = ai[s] - pk * kV;
      P.scores[b * 5 + s] = av[s];
      P.prevK[b * 5 + s] = pk; P.tokv[b * 5 + s] = tk;
      fpk[s] = pk; ftok[s] = tk;
    }
  }
  __syncthreads();
  for (int i = tid; i < 5 * BUFL; i += 256) {
    int j = i / BUFL, p = i - j * BUFL;
    int src = b * 5 + fpk[j];
    int val = (p == t + 1) ? ftok[j] : bufc[src * BUFL + p];
    bufn[(b * 5 + j) * BUFL + p] = val;
  }
}

// ---------------- the megakernel ----------------
template<bool WT, bool ET>
__global__ __launch_bounds__(256, 1) void mega_k(KParams P) {
  __shared__ float SM[16384];   // 64 KB
  const int bid = blockIdx.x, tid = threadIdx.x;
  int ph = 0;
  int* arr = P.arrive; int* rel = P.release;

  if (WT) do_transposes(P, SM);
  gbar(arr, rel, ph);
  do_crosskv<WT>(P, SM);
  gbar(arr, rel, ph);

  for (int t = 0; t < TMAX; ++t) {
    const int* bc = (t & 1) ? P.bufs1 : P.bufs0;
    int* bn = (t & 1) ? P.bufs0 : P.bufs1;
    const int np = (t + 1) & 1, op = t & 1;
    for (int l = 0; l < 2; ++l) {
      float* kNew = P.kcB + (size_t)(np * 2 + l) * CSEG;
      float* vNew = P.vcB + (size_t)(np * 2 + l) * CSEG;
      // ---- P1: QKV (+embed/LN or LN3-fused; l==0 also does cache reorder for both layers)
      if (l == 0) {
        if (bid < 18) {
          gemm_tile<WT>(SM, bid, P.siT, 2304, P.siW, 768, 0, P.siB, true,
                        1, nullptr, 0, nullptr, nullptr, 0,
                        P.lneg, P.lneb, P.XA, 3, P.qb, 768,
                        kNew, vNew, t, bc, P.emb, P.pos);
        } else if (bid >= 128 && t > 0) {
          const int nfl4 = t * 192;
          const int tot = 2 * 2 * RR * nfl4;
          for (int i = (bid - 128) * 256 + tid; i < tot; i += 128 * 256) {
            int lyr = i / (2 * RR * nfl4); int rem = i - lyr * (2 * RR * nfl4);
            int half = rem / (RR * nfl4); rem -= half * (RR * nfl4);
            int r = rem / nfl4; int e = rem - r * nfl4;
            int p = e / 192, d4 = e - p * 192;
            int src = (r / 5) * 5 + P.prevK[r];
            const float* ob = (half ? P.vcB : P.kcB) + (size_t)(op * 2 + lyr) * CSEG;
            float* nb2 = (half ? P.vcB : P.kcB) + (size_t)(np * 2 + lyr) * CSEG;
            *(float4*)&nb2[(r * BUFL + p) * 768 + d4 * 4] =
                *(const float4*)&ob[(src * BUFL + p) * 768 + d4 * 4];
          }
        }
      } else {
        if (bid < 18) {
          const float* parts[4] = {P.fp0, P.fp1, P.fp2, P.fp3};
          gemm_tile<WT>(SM, bid, P.siT + (size_t)768 * 2304, 2304, P.siW + (size_t)2304 * 768, 768, 0,
                        P.siB + 2304, true,
                        2, nullptr, 0, P.XC, parts, 4,
                        P.ln3g, P.ln3b, P.XA, 3, P.qb, 768,
                        kNew, vNew, t, bc, P.emb, P.pos);
        }
      }
      gbar(arr, rel, ph);
      // ---- P2: self-attn
      if (bid < 60) self_attn_phase(P, SM, kNew, vNew, t);
      gbar(arr, rel, ph);
      // ---- P3: self out-proj -> tmp
      if (bid < 6) {
        gemm_tile<WT>(SM, bid, P.soT + (size_t)l * 768 * 768, 768, P.soW + (size_t)l * 768 * 768, 768, 0,
                      P.soB + l * 768, true,
                      0, P.attnb, 768, nullptr, nullptr, 0,
                      nullptr, nullptr, nullptr, 0, P.tmp, 768,
                      nullptr, nullptr, t, nullptr, nullptr, nullptr);
      }
      gbar(arr, rel, ph);
      // ---- P4: LN1 + cross-q -> qb (writes XB)
      if (bid < 6) {
        const float* parts[4] = {P.tmp, nullptr, nullptr, nullptr};
        gemm_tile<WT>(SM, bid, P.ciT + (size_t)l * 768 * 2304, 2304, P.ciW + (size_t)l * 2304 * 768, 768, 0,
                      P.ciB + l * 2304, true,
                      2, nullptr, 0, P.XA, parts, 1,
                      P.ln1g + l * 768, P.ln1b + l * 768, P.XB, 0, P.qb, 768,
                      nullptr, nullptr, t, nullptr, nullptr, nullptr);
      }
      gbar(arr, rel, ph);
      // ---- P5: cross-attn
      if (bid < 60) cross_attn_phase(P, SM, P.ck + (size_t)l * 4 * 128 * 768, P.cv + (size_t)l * 4 * 128 * 768);
      gbar(arr, rel, ph);
      // ---- P6: cross out-proj -> tmp
      if (bid < 6) {
        gemm_tile<WT>(SM, bid, P.coT + (size_t)l * 768 * 768, 768, P.coW + (size_t)l * 768 * 768, 768, 0,
                      P.coB + l * 768, true,
                      0, P.attnb, 768, nullptr, nullptr, 0,
                      nullptr, nullptr, nullptr, 0, P.tmp, 768,
                      nullptr, nullptr, t, nullptr, nullptr, nullptr);
      }
      gbar(arr, rel, ph);
      // ---- P7: LN2 + ff1 (relu) -> ffb (writes XC)
      if (bid < 24) {
        const float* parts[4] = {P.tmp, nullptr, nullptr, nullptr};
        gemm_tile<WT>(SM, bid, P.f1T + (size_t)l * 768 * 3072, 3072, P.f1W + (size_t)l * 3072 * 768, 768, 0,
                      P.f1B + l * 3072, true,
                      2, nullptr, 0, P.XB, parts, 1,
                      P.ln2g + l * 768, P.ln2b + l * 768, P.XC, 1, P.ffb, 3072,
                      nullptr, nullptr, t, nullptr, nullptr, nullptr);
      }
      gbar(arr, rel, ph);
      // ---- P8: ff2 -> 4 K-quarter partials fp0..3
      if (bid < 24) {
        const int tile = bid >> 2, kq = bid & 3;
        float* fps[4] = {P.fp0, P.fp1, P.fp2, P.fp3};
        gemm_tile<WT>(SM, tile, P.f2T + (size_t)l * 3072 * 768, 768, P.f2W + (size_t)l * 768 * 3072, 3072,
                      kq * 768, P.f2B + l * 768, (kq == 0),
                      0, P.ffb + kq * 768, 3072, nullptr, nullptr, 0,
                      nullptr, nullptr, nullptr, 0, fps[kq], 768,
                      nullptr, nullptr, t, nullptr, nullptr, nullptr);
      }
      gbar(arr, rel, ph);
    }
    // ---- P17: LN3(l1) + dense (tanh) -> hbuf
    if (bid < 6) {
      const float* parts[4] = {P.fp0, P.fp1, P.fp2, P.fp3};
      gemm_tile<WT>(SM, bid, P.dT, 768, P.dW, 768, 0, P.dB, true,
                    2, nullptr, 0, P.XC, parts, 4,
                    P.ln3g + 768, P.ln3b + 768, nullptr, 2, P.hbuf, 768,
                    nullptr, nullptr, t, nullptr, nullptr, nullptr);
    }
    gbar(arr, rel, ph);
    // ---- P18: logits partials
    if (bid < LB) logits_phase<ET>(P, SM);
    gbar(arr, rel, ph);
    // ---- P19: topk + buf reorder
    if (bid < 4) topk_phase(P, SM, bc, bn, t);
    gbar(arr, rel, ph);
  }
  // ---- finalize
  if (bid == 0 && tid < RR) {
    P.out[tid] = P.scores[tid];
    int seen = 0;
    for (int i = 0; i < TMAX; ++i) {
      int tk = P.bufs0[tid * BUFL + 1 + i];
      if (tk == EOSt) seen = 1;
      P.out[RR + tid * TMAX + i] = seen ? 0.f : (float)tk;
    }
  }
}

// ---------------- init kernel ----------------
__global__ void init2_k(int* arrive, int* release, int* buf0, float* scores) {
  int tid = threadIdx.x;
  if (tid < 256) arrive[tid] = 0;
  if (tid == 0) *release = 0;
  if (tid < RR * BUFL) buf0[tid] = 0;
  __syncthreads();
  if (tid < BB) buf0[tid * BEAM * BUFL] = SOS;
  if (tid < RR) scores[tid] = (tid % BEAM == 0) ? 0.f : NEGV;
}

// ================= host side =================
extern "C" void kernel_launch(void* const* d_in, const int* in_sizes, int n_in,
                              void* d_out, int out_size, void* d_ws, size_t ws_size,
                              hipStream_t stream) {
  KParams P;
  P.emb  = (const float*)d_in[0];  P.pos  = (const float*)d_in[1];
  P.lneg = (const float*)d_in[2];  P.lneb = (const float*)d_in[3];
  P.siW  = (const float*)d_in[4];  P.siB  = (const float*)d_in[5];
  P.soW  = (const float*)d_in[6];  P.soB  = (const float*)d_in[7];
  P.ciW  = (const float*)d_in[8];  P.ciB  = (const float*)d_in[9];
  P.coW  = (const float*)d_in[10]; P.coB  = (const float*)d_in[11];
  P.f1W  = (const float*)d_in[12]; P.f1B  = (const float*)d_in[13];
  P.f2W  = (const float*)d_in[14]; P.f2B  = (const float*)d_in[15];
  P.ln1g = (const float*)d_in[16]; P.ln1b = (const float*)d_in[17];
  P.ln2g = (const float*)d_in[18]; P.ln2b = (const float*)d_in[19];
  P.ln3g = (const float*)d_in[20]; P.ln3b = (const float*)d_in[21];
  P.dW   = (const float*)d_in[22]; P.dB   = (const float*)d_in[23];
  P.ctx  = (const float*)d_in[24]; P.smask = (const int*)d_in[25];
  P.out  = (float*)d_out;

  float* wsf = (float*)d_ws;
  size_t off = 0;
  auto alloc = [&](size_t n) { float* p = wsf + off; off += (n + 3) & ~(size_t)3; return p; };

  P.arrive = (int*)alloc(256);
  P.release= (int*)alloc(8);
  P.XA    = alloc(RR * 768);
  P.XB    = alloc(RR * 768);
  P.XC    = alloc(RR * 768);
  P.qb    = alloc(RR * 768);
  P.attnb = alloc(RR * 768);
  P.tmp   = alloc(RR * 768);
  P.hbuf  = alloc(RR * 768);
  P.ffb   = alloc(RR * 3072);
  P.fp0   = alloc(RR * 768);
  P.fp1   = alloc(RR * 768);
  P.fp2   = alloc(RR * 768);
  P.fp3   = alloc(RR * 768);
  P.candV = alloc(RR * LB * 5);
  P.mrow  = alloc(RR * LB);
  P.srow  = alloc(RR * LB);
  P.scores= alloc(32);
  P.ck    = alloc((size_t)2 * 4 * 128 * 768);
  P.cv    = alloc((size_t)2 * 4 * 128 * 768);
  P.kcB   = alloc((size_t)4 * CSEG);
  P.vcB   = alloc((size_t)4 * CSEG);
  P.candI = (int*)alloc(RR * LB * 5);
  P.bufs0 = (int*)alloc(RR * BUFL + 12);
  P.bufs1 = (int*)alloc(RR * BUFL + 12);
  P.prevK = (int*)alloc(32);
  P.tokv  = (int*)alloc(32);
  const size_t baseFloats = off;

  const size_t nSiT = (size_t)768 * 2304, nSoT = (size_t)768 * 768;
  const size_t nF1T = (size_t)768 * 3072;
  const size_t wtFloats = 2 * (2 * nSiT + 2 * nSoT + 2 * nF1T) + nSoT;  // si+ci, so+co, f1+f2, dense
  const size_t embTFloats = (size_t)768 * kVP;
  const bool useWT = ws_size >= (baseFloats + wtFloats) * 4;
  const bool useET = useWT && ws_size >= (baseFloats + wtFloats + embTFloats) * 4;
  P.useWT = useWT; P.useET = useET;

  P.siT = P.soT = P.ciT = P.coT = P.f1T = P.f2T = P.dT = P.embT = nullptr;
  if (useWT) {
    P.siT = alloc(2 * nSiT);
    P.soT = alloc(2 * nSoT);
    P.ciT = alloc(2 * nSiT);
    P.coT = alloc(2 * nSoT);
    P.f1T = alloc(2 * nF1T);
    P.f2T = alloc(2 * nF1T);
    P.dT  = alloc(nSoT);
    if (useET) P.embT = alloc(embTFloats);
  }

  init2_k<<<1, 512, 0, stream>>>(P.arrive, P.release, P.bufs0, P.scores);
  if (useET)      mega_k<true, true><<<256, 256, 0, stream>>>(P);
  else if (useWT) mega_k<true, false><<<256, 256, 0, stream>>>(P);
  else            mega_k<false, false><<<256, 256, 0, stream>>>(P);
}